// Round 6
// baseline (317.290 us; speedup 1.0000x reference)
//
#include <hip/hip_runtime.h>
#include <stdint.h>

#define IN_F 4096
#define OUT_F 4096
#define M_TOT 8192
#define LORA_SCALE 4.0f   // ALPHA / RANK = 32 / 8

typedef unsigned short u16;
typedef __attribute__((ext_vector_type(8))) short bf16x8;   // 8 bf16 = 4 VGPRs
typedef __attribute__((ext_vector_type(4))) float f32x4;
typedef __attribute__((ext_vector_type(16))) float f32x16;

__device__ __forceinline__ u16 f2bf(float f) {
  union { float f; unsigned u; } v; v.f = f;
  unsigned r = v.u + 0x7FFFu + ((v.u >> 16) & 1u);  // round-to-nearest-even
  return (u16)(r >> 16);
}

__device__ __forceinline__ void gload_lds16(const void* g, void* l) {
  __builtin_amdgcn_global_load_lds(
      (const __attribute__((address_space(1))) void*)g,
      (__attribute__((address_space(3))) void*)l, 16, 0, 0);
}

// ---------------------------------------------------------------------------
// Fused prep: blocks [0, 16384)   : Xb = bf16(x)            (8 elems/thread)
//             blocks [16384, 32768): Wb = bf16(W + 4*a@b)   (4 elems/thread)
__global__ void prep(const float* __restrict__ X, const float* __restrict__ W,
                     const float* __restrict__ A, const float* __restrict__ B,
                     u16* __restrict__ Xb, u16* __restrict__ Wb) {
  int bid = blockIdx.x;
  if (bid < 16384) {
    size_t base = ((size_t)bid * blockDim.x + threadIdx.x) * 8;
    const f32x4* p = (const f32x4*)(X + base);
    f32x4 v0 = __builtin_nontemporal_load(p);
    f32x4 v1 = __builtin_nontemporal_load(p + 1);
    uint4 pk;
    pk.x = (unsigned)f2bf(v0.x) | ((unsigned)f2bf(v0.y) << 16);
    pk.y = (unsigned)f2bf(v0.z) | ((unsigned)f2bf(v0.w) << 16);
    pk.z = (unsigned)f2bf(v1.x) | ((unsigned)f2bf(v1.y) << 16);
    pk.w = (unsigned)f2bf(v1.z) | ((unsigned)f2bf(v1.w) << 16);
    *(uint4*)(Xb + base) = pk;
  } else {
    int idx = (bid - 16384) * blockDim.x + threadIdx.x;
    int o  = idx >> 10;
    int i0 = (idx & 1023) << 2;
    const f32x4 w = __builtin_nontemporal_load((const f32x4*)(W + (size_t)o * IN_F + i0));
    float a0 = w.x, a1 = w.y, a2 = w.z, a3 = w.w;
#pragma unroll
    for (int r = 0; r < 8; ++r) {
      float ar = A[o * 8 + r] * LORA_SCALE;
      const float4 bv = *(const float4*)(B + (size_t)r * IN_F + i0);
      a0 += ar * bv.x; a1 += ar * bv.y; a2 += ar * bv.z; a3 += ar * bv.w;
    }
    uint2 pk;
    pk.x = (unsigned)f2bf(a0) | ((unsigned)f2bf(a1) << 16);
    pk.y = (unsigned)f2bf(a2) | ((unsigned)f2bf(a3) << 16);
    *(uint2*)(Wb + (size_t)o * IN_F + i0) = pk;
  }
}

// ---------------------------------------------------------------------------
// GEMM: 256x256 tile, BK=64, 8 waves (2Mx4N), single-barrier 8-phase schedule,
// counted vmcnt (T4), XOR-swizzled LDS (T2), setprio (T5), XCD swizzle (T1),
// 32x32x16 MFMA.
//
// SWIZZLE (round-6 fix): f(row) = (row&7) ^ (2*((row>>4)&1)).
// The 32x32 read has khi varying only per 32 lanes; with f=row&7 the four
// 16-lane groups used only 2 distinct XOR constants -> 2.5e7 bank conflicts
// (round 5). Adding the (row>>4)&1 bit restores 4 distinct constants per
// instruction -- the address multiset becomes identical to the proven
// 0-conflict 16x16 pattern. Staging source and read offsets both use f.

#define ABASE(b) ((b) * 32768)
#define BBASE(b) ((b) * 32768 + 16384)

#define STAGE_A(b, h, kt) do { \
  gload_lds16(aG + (size_t)((h) * 128) * IN_F + (kt),      lds + ABASE(b) + ((h) * 128) * 64      + tid * 8); \
  gload_lds16(aG + (size_t)((h) * 128 + 64) * IN_F + (kt), lds + ABASE(b) + ((h) * 128 + 64) * 64 + tid * 8); \
} while (0)

#define STAGE_B(b, h, kt) do { \
  gload_lds16(bG + (size_t)((h) * 128) * IN_F + (kt),      lds + BBASE(b) + ((h) * 128) * 64      + tid * 8); \
  gload_lds16(bG + (size_t)((h) * 128 + 64) * IN_F + (kt), lds + BBASE(b) + ((h) * 128 + 64) * 64 + tid * 8); \
} while (0)

#define WAIT4 asm volatile("s_waitcnt vmcnt(4)" ::: "memory")
#define WAIT0 asm volatile("s_waitcnt vmcnt(0)" ::: "memory")
#define DRAIN asm volatile("s_waitcnt lgkmcnt(0)" ::: "memory")

#define MFMA32 __builtin_amdgcn_mfma_f32_32x32x16_bf16

#define PHASE32(b, p, STAGE_STMT) do { \
  __builtin_amdgcn_s_barrier(); \
  __builtin_amdgcn_sched_barrier(0); \
  bf16x8 a0 = *(const bf16x8*)(lds + ABASE(b) + (rA +  0) * 64 + ck[p]); \
  bf16x8 a1 = *(const bf16x8*)(lds + ABASE(b) + (rA + 32) * 64 + ck[p]); \
  bf16x8 a2 = *(const bf16x8*)(lds + ABASE(b) + (rA + 64) * 64 + ck[p]); \
  bf16x8 a3 = *(const bf16x8*)(lds + ABASE(b) + (rA + 96) * 64 + ck[p]); \
  if ((p) == 0) { \
    _Pragma("unroll") \
    for (int s = 0; s < 4; ++s) { \
      bb0[s] = *(const bf16x8*)(lds + BBASE(b) + rB * 64 + ck[s]); \
      bb1[s] = *(const bf16x8*)(lds + BBASE(b) + (rB + 32) * 64 + ck[s]); \
    } \
  } \
  STAGE_STMT; \
  __builtin_amdgcn_s_setprio(1); \
  acc[0][0] = MFMA32(a0, bb0[p], acc[0][0], 0, 0, 0); \
  acc[1][0] = MFMA32(a1, bb0[p], acc[1][0], 0, 0, 0); \
  acc[2][0] = MFMA32(a2, bb0[p], acc[2][0], 0, 0, 0); \
  acc[3][0] = MFMA32(a3, bb0[p], acc[3][0], 0, 0, 0); \
  acc[0][1] = MFMA32(a0, bb1[p], acc[0][1], 0, 0, 0); \
  acc[1][1] = MFMA32(a1, bb1[p], acc[1][1], 0, 0, 0); \
  acc[2][1] = MFMA32(a2, bb1[p], acc[2][1], 0, 0, 0); \
  acc[3][1] = MFMA32(a3, bb1[p], acc[3][1], 0, 0, 0); \
  __builtin_amdgcn_s_setprio(0); \
} while (0)

__global__ __launch_bounds__(512, 2) void gemm8(const u16* __restrict__ Xb,
                                                const u16* __restrict__ Wb,
                                                const float* __restrict__ bias,
                                                float* __restrict__ out) {
  extern __shared__ u16 lds[];

  const int tid  = threadIdx.x;
  const int lane = tid & 63;
  const int wid  = tid >> 6;
  const int wr = wid >> 2, wc = wid & 3;       // 2x4 waves, 128x64 C each
  const int l31 = lane & 31, khi = lane >> 5;

  // XCD-aware swizzle: nwg = 512, divisible by 8
  const int bid = blockIdx.x;
  const int swz = (bid & 7) * 64 + (bid >> 3);
  const int mt = swz >> 4, nt = swz & 15;       // 32 M-tiles x 16 N-tiles
  const int m0 = mt * 256, n0 = nt * 256;

  // staging: LDS dest linear; global source pre-swizzled chunk ^ f(row),
  // f(row) = (row&7) ^ (2*((row>>4)&1)). Rows staged at +64/+128 offsets
  // keep the same f (those offsets don't touch bits 0-2 / bit-4 parity).
  const int srow = tid >> 3;                                  // 0..63
  const int swc  = (tid & 7) ^ (srow & 7) ^ (2 * ((srow >> 4) & 1));
  const u16* aG = Xb + (size_t)(m0 + srow) * IN_F + swc * 8;
  const u16* bG = Wb + (size_t)(n0 + srow) * IN_F + swc * 8;

  // fragment geometry (32x32x16): A row = lane&31, logical k-chunk =
  // 2*slice + khi; LDS col = chunk ^ f(row), f(row) as above
  // (row&7 == lane&7, (row>>4)&1 == (l31>>4)&1 for all frag row offsets).
  const int rA = wr * 128 + l31;
  const int rB = wc * 64 + l31;
  const int fx = (lane & 7) ^ (2 * ((l31 >> 4) & 1));
  const int ck[4] = { ((0 + khi) ^ fx) * 8,
                      ((2 + khi) ^ fx) * 8,
                      ((4 + khi) ^ fx) * 8,
                      ((6 + khi) ^ fx) * 8 };

  f32x16 acc[4][2] = {};
  bf16x8 bb0[4], bb1[4];

  // prologue: tile0.{B,A}, tile1.B staged; wait tile0 landed
  STAGE_B(0, 0, 0); STAGE_B(0, 1, 0);
  STAGE_A(0, 0, 0); STAGE_A(0, 1, 0);
  STAGE_B(1, 0, 64); STAGE_B(1, 1, 64);
  WAIT4;

  for (int i = 0; i < 31; ++i) {
    const int kt1 = i * 128 + 64, kt2 = i * 128 + 128, kt3 = i * 128 + 192;
    // tile 2i (buffer 0)
    PHASE32(0, 0, STAGE_A(1, 0, kt1));
    PHASE32(0, 1, STAGE_A(1, 1, kt1));
    DRAIN;
    PHASE32(0, 2, STAGE_B(0, 0, kt2));
    PHASE32(0, 3, STAGE_B(0, 1, kt2));
    WAIT4;
    // tile 2i+1 (buffer 1)
    PHASE32(1, 0, STAGE_A(0, 0, kt2));
    PHASE32(1, 1, STAGE_A(0, 1, kt2));
    DRAIN;
    PHASE32(1, 2, STAGE_B(1, 0, kt3));
    PHASE32(1, 3, STAGE_B(1, 1, kt3));
    WAIT4;
  }
  // tile 62 (buf 0): stage A for tile 63 only, then drain
  PHASE32(0, 0, STAGE_A(1, 0, 4032));
  PHASE32(0, 1, STAGE_A(1, 1, 4032));
  PHASE32(0, 2, );
  PHASE32(0, 3, );
  WAIT0;
  // tile 63 (buf 1): pure compute
  PHASE32(1, 0, );
  PHASE32(1, 1, );
  PHASE32(1, 2, );
  PHASE32(1, 3, );

  // Epilogue. 32x32 C/D layout: col = lane&31, row = (reg&3)+8*(reg>>2)+4*khi
  const float bv0 = bias[n0 + wc * 64 + l31];
  const float bv1 = bias[n0 + wc * 64 + 32 + l31];
  const size_t colbase = (size_t)n0 + wc * 64 + l31;
  const int rowbase = m0 + wr * 128 + 4 * khi;
#pragma unroll
  for (int mb = 0; mb < 4; ++mb)
#pragma unroll
    for (int reg = 0; reg < 16; ++reg) {
      int row = rowbase + mb * 32 + (reg & 3) + 8 * (reg >> 2);
      __builtin_nontemporal_store(acc[mb][0][reg] + bv0,
                                  &out[(size_t)row * OUT_F + colbase]);
      __builtin_nontemporal_store(acc[mb][1][reg] + bv1,
                                  &out[(size_t)row * OUT_F + colbase + 32]);
    }
}

// ---------------------------------------------------------------------------
// Fallback GEMM (proven round-1 kernel): 128x128 tile, m97 structure, 859 TF.
__global__ __launch_bounds__(256) void gemm_bias(const u16* __restrict__ Xb,
                                                 const u16* __restrict__ Wb,
                                                 const float* __restrict__ bias,
                                                 float* __restrict__ out) {
  __shared__ __align__(16) u16 ldsA[128 * 64];
  __shared__ __align__(16) u16 ldsB[128 * 64];

  const int tid  = threadIdx.x;
  const int wid  = tid >> 6;
  const int lane = tid & 63;
  const int nt = blockIdx.x & 31;
  const int mt = blockIdx.x >> 5;
  const int m0 = mt * 128, n0 = nt * 128;
  const int wr = wid >> 1, wc = wid & 1;
  const int lr = lane & 15;
  const int kg = lane >> 4;

  const int srow   = wid * 8 + (lane >> 3);
  const int schunk = (lane & 7) ^ (srow & 7);
  const u16* aSrc = Xb + (size_t)(m0 + srow) * IN_F + schunk * 8;
  const u16* bSrc = Wb + (size_t)(n0 + srow) * IN_F + schunk * 8;

  f32x4 acc[4][4] = {};

  for (int kt = 0; kt < IN_F; kt += 64) {
    __syncthreads();
#pragma unroll
    for (int j = 0; j < 4; ++j) {
      gload_lds16(aSrc + (size_t)(j * 32) * IN_F + kt, &ldsA[j * 2048 + wid * 512]);
      gload_lds16(bSrc + (size_t)(j * 32) * IN_F + kt, &ldsB[j * 2048 + wid * 512]);
    }
    __syncthreads();

#pragma unroll
    for (int s = 0; s < 2; ++s) {
      bf16x8 af[4], bfr[4];
#pragma unroll
      for (int m = 0; m < 4; ++m) {
        int r = wr * 64 + m * 16 + lr;
        int c = (s * 4 + kg) ^ (r & 7);
        af[m] = *(const bf16x8*)&ldsA[r * 64 + c * 8];
      }
#pragma unroll
      for (int n = 0; n < 4; ++n) {
        int r = wc * 64 + n * 16 + lr;
        int c = (s * 4 + kg) ^ (r & 7);
        bfr[n] = *(const bf16x8*)&ldsB[r * 64 + c * 8];
      }
#pragma unroll
      for (int m = 0; m < 4; ++m)
#pragma unroll
        for (int n = 0; n < 4; ++n)
          acc[m][n] = __builtin_amdgcn_mfma_f32_16x16x32_bf16(af[m], bfr[n], acc[m][n], 0, 0, 0);
    }
  }

  float bv[4];
#pragma unroll
  for (int n = 0; n < 4; ++n) bv[n] = bias[n0 + wc * 64 + n * 16 + lr];
  const int rbase = m0 + wr * 64 + kg * 4;
#pragma unroll
  for (int m = 0; m < 4; ++m)
#pragma unroll
    for (int n = 0; n < 4; ++n) {
      int col = n0 + wc * 64 + n * 16 + lr;
#pragma unroll
      for (int r = 0; r < 4; ++r)
        out[(size_t)(rbase + m * 16 + r) * OUT_F + col] = acc[m][n][r] + bv[n];
    }
}

// ---------------------------------------------------------------------------
// fp32 fallback (tiny workspace): exact, slow but correct.
__global__ void lora_t(const float* __restrict__ x, const float* __restrict__ B,
                       float* __restrict__ t) {
  int m = blockIdx.x;
  int tid = threadIdx.x, lane = tid & 63;
  float p[8] = {0, 0, 0, 0, 0, 0, 0, 0};
  for (int k = tid; k < IN_F; k += 256) {
    float xv = x[(size_t)m * IN_F + k];
#pragma unroll
    for (int r = 0; r < 8; ++r) p[r] += xv * B[r * IN_F + k];
  }
#pragma unroll
  for (int r = 0; r < 8; ++r) {
    float v = p[r];
    for (int off = 32; off; off >>= 1) v += __shfl_down(v, off);
    if (lane == 0) atomicAdd(&t[m * 8 + r], v);
  }
}

__global__ void fb_gemm(const float* __restrict__ x, const float* __restrict__ W,
                        const float* __restrict__ A, const float* __restrict__ bias,
                        const float* __restrict__ t, float* __restrict__ out) {
  __shared__ float sx[64][17];
  __shared__ float sw[64][17];
  int tx = threadIdx.x, ty = threadIdx.y;
  int tid = ty * 16 + tx;
  int m0 = blockIdx.y * 64, n0 = blockIdx.x * 64;
  float acc[4][4] = {};
  for (int kt = 0; kt < IN_F; kt += 16) {
    __syncthreads();
#pragma unroll
    for (int q = 0; q < 4; ++q) {
      int idx = q * 256 + tid;
      int r = idx >> 4, c = idx & 15;
      sx[r][c] = x[(size_t)(m0 + r) * IN_F + kt + c];
      sw[r][c] = W[(size_t)(n0 + r) * IN_F + kt + c];
    }
    __syncthreads();
#pragma unroll
    for (int k = 0; k < 16; ++k) {
      float xv[4], wv[4];
#pragma unroll
      for (int i = 0; i < 4; ++i) xv[i] = sx[ty * 4 + i][k];
#pragma unroll
      for (int j = 0; j < 4; ++j) wv[j] = sw[tx * 4 + j][k];
#pragma unroll
      for (int i = 0; i < 4; ++i)
#pragma unroll
        for (int j = 0; j < 4; ++j) acc[i][j] += xv[i] * wv[j];
    }
  }
#pragma unroll
  for (int i = 0; i < 4; ++i) {
    int m = m0 + ty * 4 + i;
    float tv[8];
#pragma unroll
    for (int r = 0; r < 8; ++r) tv[r] = t[m * 8 + r];
#pragma unroll
    for (int j = 0; j < 4; ++j) {
      int o = n0 + tx * 4 + j;
      float lora = 0.f;
#pragma unroll
      for (int r = 0; r < 8; ++r) lora += tv[r] * A[o * 8 + r];
      out[(size_t)m * OUT_F + o] = acc[i][j] + bias[o] + LORA_SCALE * lora;
    }
  }
}

// ---------------------------------------------------------------------------
extern "C" void kernel_launch(void* const* d_in, const int* in_sizes, int n_in,
                              void* d_out, int out_size, void* d_ws, size_t ws_size,
                              hipStream_t stream) {
  const float* x    = (const float*)d_in[0];
  const float* W    = (const float*)d_in[1];
  const float* A    = (const float*)d_in[2];
  const float* B    = (const float*)d_in[3];
  const float* bias = (const float*)d_in[4];
  float* out = (float*)d_out;

  const size_t xb_elems = (size_t)M_TOT * IN_F;
  const size_t wb_elems = (size_t)OUT_F * IN_F;
  const size_t need = (xb_elems + wb_elems) * sizeof(u16);

  if (ws_size >= need) {
    u16* Xb = (u16*)d_ws;
    u16* Wb = Xb + xb_elems;
    prep<<<32768, 256, 0, stream>>>(x, W, A, B, Xb, Wb);

    hipError_t e = hipFuncSetAttribute((const void*)gemm8,
                                       hipFuncAttributeMaxDynamicSharedMemorySize,
                                       131072);
    bool used8 = false;
    if (e == hipSuccess) {
      gemm8<<<512, 512, 131072, stream>>>(Xb, Wb, bias, out);
      used8 = (hipGetLastError() == hipSuccess);
    }
    if (!used8) {
      gemm_bias<<<(M_TOT / 128) * (OUT_F / 128), 256, 0, stream>>>(Xb, Wb, bias, out);
    }
  } else {
    float* t = (float*)d_ws;
    (void)hipMemsetAsync(t, 0, (size_t)M_TOT * 8 * sizeof(float), stream);
    lora_t<<<M_TOT, 256, 0, stream>>>(x, B, t);
    fb_gemm<<<dim3(OUT_F / 64, M_TOT / 64), dim3(16, 16), 0, stream>>>(x, W, A, bias, t, out);
  }
}

// Round 7
// 295.993 us; speedup vs baseline: 1.0720x; 1.0720x over previous
//
#include <hip/hip_runtime.h>
#include <stdint.h>

#define IN_F 4096
#define OUT_F 4096
#define M_TOT 8192
#define LORA_SCALE 4.0f   // ALPHA / RANK = 32 / 8

typedef unsigned short u16;
typedef __attribute__((ext_vector_type(8))) short bf16x8;   // 8 bf16 = 4 VGPRs
typedef __attribute__((ext_vector_type(4))) float f32x4;

__device__ __forceinline__ u16 f2bf(float f) {
  union { float f; unsigned u; } v; v.f = f;
  unsigned r = v.u + 0x7FFFu + ((v.u >> 16) & 1u);  // round-to-nearest-even
  return (u16)(r >> 16);
}

__device__ __forceinline__ void gload_lds16(const void* g, void* l) {
  __builtin_amdgcn_global_load_lds(
      (const __attribute__((address_space(1))) void*)g,
      (__attribute__((address_space(3))) void*)l, 16, 0, 0);
}

// ---------------------------------------------------------------------------
// Fused prep: blocks [0, 16384)   : Xb = bf16(x)            (8 elems/thread)
//             blocks [16384, 32768): Wb = bf16(W + 4*a@b)   (4 elems/thread)
__global__ void prep(const float* __restrict__ X, const float* __restrict__ W,
                     const float* __restrict__ A, const float* __restrict__ B,
                     u16* __restrict__ Xb, u16* __restrict__ Wb) {
  int bid = blockIdx.x;
  if (bid < 16384) {
    size_t base = ((size_t)bid * blockDim.x + threadIdx.x) * 8;
    const f32x4* p = (const f32x4*)(X + base);
    f32x4 v0 = __builtin_nontemporal_load(p);
    f32x4 v1 = __builtin_nontemporal_load(p + 1);
    uint4 pk;
    pk.x = (unsigned)f2bf(v0.x) | ((unsigned)f2bf(v0.y) << 16);
    pk.y = (unsigned)f2bf(v0.z) | ((unsigned)f2bf(v0.w) << 16);
    pk.z = (unsigned)f2bf(v1.x) | ((unsigned)f2bf(v1.y) << 16);
    pk.w = (unsigned)f2bf(v1.z) | ((unsigned)f2bf(v1.w) << 16);
    *(uint4*)(Xb + base) = pk;
  } else {
    int idx = (bid - 16384) * blockDim.x + threadIdx.x;
    int o  = idx >> 10;
    int i0 = (idx & 1023) << 2;
    const f32x4 w = __builtin_nontemporal_load((const f32x4*)(W + (size_t)o * IN_F + i0));
    float a0 = w.x, a1 = w.y, a2 = w.z, a3 = w.w;
#pragma unroll
    for (int r = 0; r < 8; ++r) {
      float ar = A[o * 8 + r] * LORA_SCALE;
      const float4 bv = *(const float4*)(B + (size_t)r * IN_F + i0);
      a0 += ar * bv.x; a1 += ar * bv.y; a2 += ar * bv.z; a3 += ar * bv.w;
    }
    uint2 pk;
    pk.x = (unsigned)f2bf(a0) | ((unsigned)f2bf(a1) << 16);
    pk.y = (unsigned)f2bf(a2) | ((unsigned)f2bf(a3) << 16);
    *(uint2*)(Wb + (size_t)o * IN_F + i0) = pk;
  }
}

// ---------------------------------------------------------------------------
// GEMM: 256x256 tile, BK=64, 8 waves (2Mx4N), single-barrier 8-phase schedule,
// counted vmcnt (T4), XOR-swizzled LDS (T2, proven 0-conflict), setprio (T5),
// XCD swizzle (T1). 16x16x32 MFMA (REVERTED from 32x32: structural conflicts).
//
// Round-7 change: LDS reads REBALANCED across phases. Old: ph0 read all 8 B
// frags + 4 A = 12 b128 (1152 cyc LDS-bound at CU level) while ph1-3 read 4.
// New: phases iterate k-slice-major -- ph0: Bf0(4)+A(4), ph1: Bf1(4)+A(4)
// (read-ahead), ph2/ph3: A(4) -- per-phase 8/8/4/4. Per-tile LDS unchanged
// (2304 cyc) but per-phase max drops: 3015 -> 2778 cyc/tile lower bound.
//
// MFMA order: ph0 = slice0 x m0-3, ph1 = slice0 x m4-7, ph2 = slice1 x m0-3,
// ph3 = slice1 x m4-7. B[b]'s LDS region is overwritten only in ph2/ph3;
// all B reads complete by end of ph1 -- enforced by DRAIN (lgkmcnt(0)) before
// ph2's barrier. A[b^1] staged ph0/ph1 was last read in prev tile's ph3.
// vmcnt schedule identical to the round-4 proven kernel.

#define ABASE(b) ((b) * 32768)
#define BBASE(b) ((b) * 32768 + 16384)

#define STAGE_A(b, h, kt) do { \
  gload_lds16(aG + (size_t)((h) * 128) * IN_F + (kt),      lds + ABASE(b) + ((h) * 128) * 64      + tid * 8); \
  gload_lds16(aG + (size_t)((h) * 128 + 64) * IN_F + (kt), lds + ABASE(b) + ((h) * 128 + 64) * 64 + tid * 8); \
} while (0)

#define STAGE_B(b, h, kt) do { \
  gload_lds16(bG + (size_t)((h) * 128) * IN_F + (kt),      lds + BBASE(b) + ((h) * 128) * 64      + tid * 8); \
  gload_lds16(bG + (size_t)((h) * 128 + 64) * IN_F + (kt), lds + BBASE(b) + ((h) * 128 + 64) * 64 + tid * 8); \
} while (0)

#define WAIT4 asm volatile("s_waitcnt vmcnt(4)" ::: "memory")
#define WAIT0 asm volatile("s_waitcnt vmcnt(0)" ::: "memory")
#define DRAIN asm volatile("s_waitcnt lgkmcnt(0)" ::: "memory")

#define MFMA16 __builtin_amdgcn_mfma_f32_16x16x32_bf16

// phase: m-half mh (0/1), k-slice s (0/1). All args compile-time literals.
#define PHASE16(b, mh, s, STAGE_STMT, TAIL_STMT) do { \
  __builtin_amdgcn_s_barrier(); \
  __builtin_amdgcn_sched_barrier(0); \
  if ((s) == 0 && (mh) == 0) { \
    _Pragma("unroll") \
    for (int n = 0; n < 4; ++n) \
      Bf0[n] = *(const bf16x8*)(lds + BBASE(b) + (rB + n * 16) * 64 + ck0); \
  } \
  if ((s) == 0 && (mh) == 1) { \
    _Pragma("unroll") \
    for (int n = 0; n < 4; ++n) \
      Bf1[n] = *(const bf16x8*)(lds + BBASE(b) + (rB + n * 16) * 64 + ck1); \
  } \
  bf16x8 a_[4]; \
  _Pragma("unroll") \
  for (int j = 0; j < 4; ++j) \
    a_[j] = *(const bf16x8*)(lds + ABASE(b) + (rA + (mh) * 64 + j * 16) * 64 + ((s) ? ck1 : ck0)); \
  STAGE_STMT; \
  __builtin_amdgcn_s_setprio(1); \
  _Pragma("unroll") \
  for (int j = 0; j < 4; ++j) \
    _Pragma("unroll") \
    for (int n = 0; n < 4; ++n) \
      acc[(mh) * 4 + j][n] = MFMA16(a_[j], ((s) ? Bf1 : Bf0)[n], acc[(mh) * 4 + j][n], 0, 0, 0); \
  __builtin_amdgcn_s_setprio(0); \
  TAIL_STMT; \
} while (0)

__global__ __launch_bounds__(512, 2) void gemm8(const u16* __restrict__ Xb,
                                                const u16* __restrict__ Wb,
                                                const float* __restrict__ bias,
                                                float* __restrict__ out) {
  extern __shared__ u16 lds[];

  const int tid  = threadIdx.x;
  const int lane = tid & 63;
  const int wid  = tid >> 6;
  const int wr = wid >> 2, wc = wid & 3;       // 2x4 waves, 128x64 C each
  const int lr = lane & 15, kg = lane >> 4;

  // XCD-aware swizzle: nwg = 512, divisible by 8
  const int bid = blockIdx.x;
  const int swz = (bid & 7) * 64 + (bid >> 3);
  const int mt = swz >> 4, nt = swz & 15;       // 32 M-tiles x 16 N-tiles
  const int m0 = mt * 256, n0 = nt * 256;

  // staging: LDS dest linear; global source pre-swizzled chunk^(row&7)
  const int srow = tid >> 3;                                  // 0..63
  const int swc  = (tid & 7) ^ (srow & 7);
  const u16* aG = Xb + (size_t)(m0 + srow) * IN_F + swc * 8;
  const u16* bG = Wb + (size_t)(n0 + srow) * IN_F + swc * 8;

  // fragment read offsets (proven 0-conflict 16x16 pattern)
  const int rA = wr * 128 + lr;
  const int rB = wc * 64 + lr;
  const int ck0 = ((kg) ^ (lane & 7)) * 8;       // k-slice 0
  const int ck1 = ((4 + kg) ^ (lane & 7)) * 8;   // k-slice 1

  f32x4 acc[8][4] = {};
  bf16x8 Bf0[4], Bf1[4];

  // prologue: tile0.{B,A}, tile1.B staged; wait tile0 landed
  STAGE_B(0, 0, 0); STAGE_B(0, 1, 0);
  STAGE_A(0, 0, 0); STAGE_A(0, 1, 0);
  STAGE_B(1, 0, 64); STAGE_B(1, 1, 64);
  WAIT4;

  for (int i = 0; i < 31; ++i) {
    const int kt1 = i * 128 + 64, kt2 = i * 128 + 128, kt3 = i * 128 + 192;
    // tile 2i (buffer 0)
    PHASE16(0, 0, 0, STAGE_A(1, 0, kt1), );
    PHASE16(0, 1, 0, STAGE_A(1, 1, kt1), DRAIN);
    PHASE16(0, 0, 1, STAGE_B(0, 0, kt2), );
    PHASE16(0, 1, 1, STAGE_B(0, 1, kt2), WAIT4);
    // tile 2i+1 (buffer 1)
    PHASE16(1, 0, 0, STAGE_A(0, 0, kt2), );
    PHASE16(1, 1, 0, STAGE_A(0, 1, kt2), DRAIN);
    PHASE16(1, 0, 1, STAGE_B(1, 0, kt3), );
    PHASE16(1, 1, 1, STAGE_B(1, 1, kt3), WAIT4);
  }
  // tile 62 (buf 0): stage A for tile 63 only, then drain
  PHASE16(0, 0, 0, STAGE_A(1, 0, 4032), );
  PHASE16(0, 1, 0, STAGE_A(1, 1, 4032), DRAIN);
  PHASE16(0, 0, 1, , );
  PHASE16(0, 1, 1, , WAIT0);
  // tile 63 (buf 1): pure compute
  PHASE16(1, 0, 0, , );
  PHASE16(1, 1, 0, , );
  PHASE16(1, 0, 1, , );
  PHASE16(1, 1, 1, , );

  // C write + bias (nontemporal). C/D layout: col = lane&15, row = kg*4 + reg
  float bv[4];
#pragma unroll
  for (int n = 0; n < 4; ++n) bv[n] = bias[n0 + wc * 64 + n * 16 + lr];
  const int rbase = m0 + wr * 128 + kg * 4;
#pragma unroll
  for (int m = 0; m < 8; ++m)
#pragma unroll
    for (int n = 0; n < 4; ++n) {
      int col = n0 + wc * 64 + n * 16 + lr;
#pragma unroll
      for (int r = 0; r < 4; ++r)
        __builtin_nontemporal_store(acc[m][n][r] + bv[n],
                                    &out[(size_t)(rbase + m * 16 + r) * OUT_F + col]);
    }
}

// ---------------------------------------------------------------------------
// Fallback GEMM (proven round-1 kernel): 128x128 tile, m97 structure, 859 TF.
__global__ __launch_bounds__(256) void gemm_bias(const u16* __restrict__ Xb,
                                                 const u16* __restrict__ Wb,
                                                 const float* __restrict__ bias,
                                                 float* __restrict__ out) {
  __shared__ __align__(16) u16 ldsA[128 * 64];
  __shared__ __align__(16) u16 ldsB[128 * 64];

  const int tid  = threadIdx.x;
  const int wid  = tid >> 6;
  const int lane = tid & 63;
  const int nt = blockIdx.x & 31;
  const int mt = blockIdx.x >> 5;
  const int m0 = mt * 128, n0 = nt * 128;
  const int wr = wid >> 1, wc = wid & 1;
  const int lr = lane & 15;
  const int kg = lane >> 4;

  const int srow   = wid * 8 + (lane >> 3);
  const int schunk = (lane & 7) ^ (srow & 7);
  const u16* aSrc = Xb + (size_t)(m0 + srow) * IN_F + schunk * 8;
  const u16* bSrc = Wb + (size_t)(n0 + srow) * IN_F + schunk * 8;

  f32x4 acc[4][4] = {};

  for (int kt = 0; kt < IN_F; kt += 64) {
    __syncthreads();
#pragma unroll
    for (int j = 0; j < 4; ++j) {
      gload_lds16(aSrc + (size_t)(j * 32) * IN_F + kt, &ldsA[j * 2048 + wid * 512]);
      gload_lds16(bSrc + (size_t)(j * 32) * IN_F + kt, &ldsB[j * 2048 + wid * 512]);
    }
    __syncthreads();

#pragma unroll
    for (int s = 0; s < 2; ++s) {
      bf16x8 af[4], bfr[4];
#pragma unroll
      for (int m = 0; m < 4; ++m) {
        int r = wr * 64 + m * 16 + lr;
        int c = (s * 4 + kg) ^ (r & 7);
        af[m] = *(const bf16x8*)&ldsA[r * 64 + c * 8];
      }
#pragma unroll
      for (int n = 0; n < 4; ++n) {
        int r = wc * 64 + n * 16 + lr;
        int c = (s * 4 + kg) ^ (r & 7);
        bfr[n] = *(const bf16x8*)&ldsB[r * 64 + c * 8];
      }
#pragma unroll
      for (int m = 0; m < 4; ++m)
#pragma unroll
        for (int n = 0; n < 4; ++n)
          acc[m][n] = __builtin_amdgcn_mfma_f32_16x16x32_bf16(af[m], bfr[n], acc[m][n], 0, 0, 0);
    }
  }

  float bv[4];
#pragma unroll
  for (int n = 0; n < 4; ++n) bv[n] = bias[n0 + wc * 64 + n * 16 + lr];
  const int rbase = m0 + wr * 64 + kg * 4;
#pragma unroll
  for (int m = 0; m < 4; ++m)
#pragma unroll
    for (int n = 0; n < 4; ++n) {
      int col = n0 + wc * 64 + n * 16 + lr;
#pragma unroll
      for (int r = 0; r < 4; ++r)
        out[(size_t)(rbase + m * 16 + r) * OUT_F + col] = acc[m][n][r] + bv[n];
    }
}

// ---------------------------------------------------------------------------
// fp32 fallback (tiny workspace): exact, slow but correct.
__global__ void lora_t(const float* __restrict__ x, const float* __restrict__ B,
                       float* __restrict__ t) {
  int m = blockIdx.x;
  int tid = threadIdx.x, lane = tid & 63;
  float p[8] = {0, 0, 0, 0, 0, 0, 0, 0};
  for (int k = tid; k < IN_F; k += 256) {
    float xv = x[(size_t)m * IN_F + k];
#pragma unroll
    for (int r = 0; r < 8; ++r) p[r] += xv * B[r * IN_F + k];
  }
#pragma unroll
  for (int r = 0; r < 8; ++r) {
    float v = p[r];
    for (int off = 32; off; off >>= 1) v += __shfl_down(v, off);
    if (lane == 0) atomicAdd(&t[m * 8 + r], v);
  }
}

__global__ void fb_gemm(const float* __restrict__ x, const float* __restrict__ W,
                        const float* __restrict__ A, const float* __restrict__ bias,
                        const float* __restrict__ t, float* __restrict__ out) {
  __shared__ float sx[64][17];
  __shared__ float sw[64][17];
  int tx = threadIdx.x, ty = threadIdx.y;
  int tid = ty * 16 + tx;
  int m0 = blockIdx.y * 64, n0 = blockIdx.x * 64;
  float acc[4][4] = {};
  for (int kt = 0; kt < IN_F; kt += 16) {
    __syncthreads();
#pragma unroll
    for (int q = 0; q < 4; ++q) {
      int idx = q * 256 + tid;
      int r = idx >> 4, c = idx & 15;
      sx[r][c] = x[(size_t)(m0 + r) * IN_F + kt + c];
      sw[r][c] = W[(size_t)(n0 + r) * IN_F + kt + c];
    }
    __syncthreads();
#pragma unroll
    for (int k = 0; k < 16; ++k) {
      float xv[4], wv[4];
#pragma unroll
      for (int i = 0; i < 4; ++i) xv[i] = sx[ty * 4 + i][k];
#pragma unroll
      for (int j = 0; j < 4; ++j) wv[j] = sw[tx * 4 + j][k];
#pragma unroll
      for (int i = 0; i < 4; ++i)
#pragma unroll
        for (int j = 0; j < 4; ++j) acc[i][j] += xv[i] * wv[j];
    }
  }
#pragma unroll
  for (int i = 0; i < 4; ++i) {
    int m = m0 + ty * 4 + i;
    float tv[8];
#pragma unroll
    for (int r = 0; r < 8; ++r) tv[r] = t[m * 8 + r];
#pragma unroll
    for (int j = 0; j < 4; ++j) {
      int o = n0 + tx * 4 + j;
      float lora = 0.f;
#pragma unroll
      for (int r = 0; r < 8; ++r) lora += tv[r] * A[o * 8 + r];
      out[(size_t)m * OUT_F + o] = acc[i][j] + bias[o] + LORA_SCALE * lora;
    }
  }
}

// ---------------------------------------------------------------------------
extern "C" void kernel_launch(void* const* d_in, const int* in_sizes, int n_in,
                              void* d_out, int out_size, void* d_ws, size_t ws_size,
                              hipStream_t stream) {
  const float* x    = (const float*)d_in[0];
  const float* W    = (const float*)d_in[1];
  const float* A    = (const float*)d_in[2];
  const float* B    = (const float*)d_in[3];
  const float* bias = (const float*)d_in[4];
  float* out = (float*)d_out;

  const size_t xb_elems = (size_t)M_TOT * IN_F;
  const size_t wb_elems = (size_t)OUT_F * IN_F;
  const size_t need = (xb_elems + wb_elems) * sizeof(u16);

  if (ws_size >= need) {
    u16* Xb = (u16*)d_ws;
    u16* Wb = Xb + xb_elems;
    prep<<<32768, 256, 0, stream>>>(x, W, A, B, Xb, Wb);

    hipError_t e = hipFuncSetAttribute((const void*)gemm8,
                                       hipFuncAttributeMaxDynamicSharedMemorySize,
                                       131072);
    bool used8 = false;
    if (e == hipSuccess) {
      gemm8<<<512, 512, 131072, stream>>>(Xb, Wb, bias, out);
      used8 = (hipGetLastError() == hipSuccess);
    }
    if (!used8) {
      gemm_bias<<<(M_TOT / 128) * (OUT_F / 128), 256, 0, stream>>>(Xb, Wb, bias, out);
    }
  } else {
    float* t = (float*)d_ws;
    (void)hipMemsetAsync(t, 0, (size_t)M_TOT * 8 * sizeof(float), stream);
    lora_t<<<M_TOT, 256, 0, stream>>>(x, B, t);
    fb_gemm<<<dim3(OUT_F / 64, M_TOT / 64), dim3(16, 16), 0, stream>>>(x, W, A, bias, t, out);
  }
}

// Round 8
// 292.564 us; speedup vs baseline: 1.0845x; 1.0117x over previous
//
#include <hip/hip_runtime.h>
#include <stdint.h>

#define IN_F 4096
#define OUT_F 4096
#define M_TOT 8192
#define LORA_SCALE 4.0f   // ALPHA / RANK = 32 / 8

typedef unsigned short u16;
typedef __attribute__((ext_vector_type(8))) short bf16x8;   // 8 bf16 = 4 VGPRs
typedef __attribute__((ext_vector_type(4))) float f32x4;

__device__ __forceinline__ u16 f2bf(float f) {
  union { float f; unsigned u; } v; v.f = f;
  unsigned r = v.u + 0x7FFFu + ((v.u >> 16) & 1u);  // round-to-nearest-even
  return (u16)(r >> 16);
}

__device__ __forceinline__ void gload_lds16(const void* g, void* l) {
  __builtin_amdgcn_global_load_lds(
      (const __attribute__((address_space(1))) void*)g,
      (__attribute__((address_space(3))) void*)l, 16, 0, 0);
}

// ---------------------------------------------------------------------------
// Fused prep: blocks [0, 16384)   : Xb = bf16(x)            (8 elems/thread)
//             blocks [16384, 32768): Wb = bf16(W + 4*a@b)   (4 elems/thread)
__global__ void prep(const float* __restrict__ X, const float* __restrict__ W,
                     const float* __restrict__ A, const float* __restrict__ B,
                     u16* __restrict__ Xb, u16* __restrict__ Wb) {
  int bid = blockIdx.x;
  if (bid < 16384) {
    size_t base = ((size_t)bid * blockDim.x + threadIdx.x) * 8;
    const f32x4* p = (const f32x4*)(X + base);
    f32x4 v0 = __builtin_nontemporal_load(p);
    f32x4 v1 = __builtin_nontemporal_load(p + 1);
    uint4 pk;
    pk.x = (unsigned)f2bf(v0.x) | ((unsigned)f2bf(v0.y) << 16);
    pk.y = (unsigned)f2bf(v0.z) | ((unsigned)f2bf(v0.w) << 16);
    pk.z = (unsigned)f2bf(v1.x) | ((unsigned)f2bf(v1.y) << 16);
    pk.w = (unsigned)f2bf(v1.z) | ((unsigned)f2bf(v1.w) << 16);
    *(uint4*)(Xb + base) = pk;
  } else {
    int idx = (bid - 16384) * blockDim.x + threadIdx.x;
    int o  = idx >> 10;
    int i0 = (idx & 1023) << 2;
    const f32x4 w = __builtin_nontemporal_load((const f32x4*)(W + (size_t)o * IN_F + i0));
    float a0 = w.x, a1 = w.y, a2 = w.z, a3 = w.w;
#pragma unroll
    for (int r = 0; r < 8; ++r) {
      float ar = A[o * 8 + r] * LORA_SCALE;
      const float4 bv = *(const float4*)(B + (size_t)r * IN_F + i0);
      a0 += ar * bv.x; a1 += ar * bv.y; a2 += ar * bv.z; a3 += ar * bv.w;
    }
    uint2 pk;
    pk.x = (unsigned)f2bf(a0) | ((unsigned)f2bf(a1) << 16);
    pk.y = (unsigned)f2bf(a2) | ((unsigned)f2bf(a3) << 16);
    *(uint2*)(Wb + (size_t)o * IN_F + i0) = pk;
  }
}

// ---------------------------------------------------------------------------
// GEMM: 256x256 tile, BK=64, 8 waves (2Mx4N), 16x16x32 MFMA.
// Round-8 structure: TWO barriers per K-tile (one per k-slice half) instead
// of four. Each half-window: {bar; 12 ds_reads (4 B + 8 A frags); 32 MFMA
// with compiler-counted lgkm interleave; stage at tail}. Rationale: with a
// barrier every 16 MFMA, all 8 waves burst-read then all MFMA -- LDS and
// matrix pipe serialize (measured 1114 cyc/phase vs 621 MFMA floor; 3 null
// schedule probes). A 2x longer window lets waves self-skew: early waves'
// MFMA streams overlap late waves' reads (separate pipes).
//
// Race audit: B[b] region overwritten only by the tail-stage of the 2nd
// half (issue ~bar+800, LDS write lands >= +500 later); all B-reads issue
// right after the barrier and complete within the read burst (<~600 cyc).
// A[b^1] tail-staged in 1st half vs its last reads issued a full half
// earlier. vmcnt schedule identical to the proven r4 kernel: prologue
// B0,A0,B1 + WAIT4; per tile WAIT4 after 2nd half (A(t+1) landed, B(t+2)
// in flight); WAIT0 before the final tile.

#define ABASE(b) ((b) * 32768)
#define BBASE(b) ((b) * 32768 + 16384)

#define STAGE_A(b, h, kt) do { \
  gload_lds16(aG + (size_t)((h) * 128) * IN_F + (kt),      lds + ABASE(b) + ((h) * 128) * 64      + tid * 8); \
  gload_lds16(aG + (size_t)((h) * 128 + 64) * IN_F + (kt), lds + ABASE(b) + ((h) * 128 + 64) * 64 + tid * 8); \
} while (0)

#define STAGE_B(b, h, kt) do { \
  gload_lds16(bG + (size_t)((h) * 128) * IN_F + (kt),      lds + BBASE(b) + ((h) * 128) * 64      + tid * 8); \
  gload_lds16(bG + (size_t)((h) * 128 + 64) * IN_F + (kt), lds + BBASE(b) + ((h) * 128 + 64) * 64 + tid * 8); \
} while (0)

#define WAIT4 asm volatile("s_waitcnt vmcnt(4)" ::: "memory")
#define WAIT0 asm volatile("s_waitcnt vmcnt(0)" ::: "memory")

#define MFMA16 __builtin_amdgcn_mfma_f32_16x16x32_bf16

// One K-tile half: k-slice s of buffer b; 12 ds_reads + 32 MFMA + tail stage.
#define KHALF(b, s, TAIL_STAGE) do { \
  __builtin_amdgcn_s_barrier(); \
  __builtin_amdgcn_sched_barrier(0); \
  _Pragma("unroll") \
  for (int n = 0; n < 4; ++n) \
    Bf[n] = *(const bf16x8*)(lds + BBASE(b) + (rB + n * 16) * 64 + ((s) ? ck1 : ck0)); \
  _Pragma("unroll") \
  for (int m = 0; m < 8; ++m) \
    Af[m] = *(const bf16x8*)(lds + ABASE(b) + (rA + m * 16) * 64 + ((s) ? ck1 : ck0)); \
  __builtin_amdgcn_s_setprio(1); \
  _Pragma("unroll") \
  for (int m = 0; m < 8; ++m) \
    _Pragma("unroll") \
    for (int n = 0; n < 4; ++n) \
      acc[m][n] = MFMA16(Af[m], Bf[n], acc[m][n], 0, 0, 0); \
  __builtin_amdgcn_s_setprio(0); \
  TAIL_STAGE; \
} while (0)

__global__ __launch_bounds__(512, 2) void gemm8(const u16* __restrict__ Xb,
                                                const u16* __restrict__ Wb,
                                                const float* __restrict__ bias,
                                                float* __restrict__ out) {
  extern __shared__ u16 lds[];

  const int tid  = threadIdx.x;
  const int lane = tid & 63;
  const int wid  = tid >> 6;
  const int wr = wid >> 2, wc = wid & 3;       // 2x4 waves, 128x64 C each
  const int lr = lane & 15, kg = lane >> 4;

  // XCD-aware swizzle: nwg = 512, divisible by 8
  const int bid = blockIdx.x;
  const int swz = (bid & 7) * 64 + (bid >> 3);
  const int mt = swz >> 4, nt = swz & 15;       // 32 M-tiles x 16 N-tiles
  const int m0 = mt * 256, n0 = nt * 256;

  // staging: LDS dest linear; global source pre-swizzled chunk^(row&7)
  const int srow = tid >> 3;                                  // 0..63
  const int swc  = (tid & 7) ^ (srow & 7);
  const u16* aG = Xb + (size_t)(m0 + srow) * IN_F + swc * 8;
  const u16* bG = Wb + (size_t)(n0 + srow) * IN_F + swc * 8;

  // fragment read offsets (proven 0-conflict 16x16 pattern)
  const int rA = wr * 128 + lr;
  const int rB = wc * 64 + lr;
  const int ck0 = ((kg) ^ (lane & 7)) * 8;       // k-slice 0
  const int ck1 = ((4 + kg) ^ (lane & 7)) * 8;   // k-slice 1

  f32x4 acc[8][4] = {};
  bf16x8 Af[8], Bf[4];

  // prologue: B0, A0, B1 staged; WAIT4 -> B0+A0 landed, B1 in flight
  STAGE_B(0, 0, 0); STAGE_B(0, 1, 0);
  STAGE_A(0, 0, 0); STAGE_A(0, 1, 0);
  STAGE_B(1, 0, 64); STAGE_B(1, 1, 64);
  WAIT4;

  for (int i = 0; i < 31; ++i) {
    const int kt1 = i * 128 + 64, kt2 = i * 128 + 128, kt3 = i * 128 + 192;
    // tile 2i (buffer 0)
    KHALF(0, 0, STAGE_A(1, 0, kt1); STAGE_A(1, 1, kt1));
    KHALF(0, 1, STAGE_B(0, 0, kt2); STAGE_B(0, 1, kt2));
    WAIT4;
    // tile 2i+1 (buffer 1)
    KHALF(1, 0, STAGE_A(0, 0, kt2); STAGE_A(0, 1, kt2));
    KHALF(1, 1, STAGE_B(1, 0, kt3); STAGE_B(1, 1, kt3));
    WAIT4;
  }
  // tile 62 (buf 0, kt=3968): stage A for tile 63 only, then drain
  KHALF(0, 0, STAGE_A(1, 0, 4032); STAGE_A(1, 1, 4032));
  KHALF(0, 1, );
  WAIT0;
  // tile 63 (buf 1, kt=4032): pure compute
  KHALF(1, 0, );
  KHALF(1, 1, );

  // C write + bias (nontemporal). C/D layout: col = lane&15, row = kg*4 + reg
  float bv[4];
#pragma unroll
  for (int n = 0; n < 4; ++n) bv[n] = bias[n0 + wc * 64 + n * 16 + lr];
  const int rbase = m0 + wr * 128 + kg * 4;
#pragma unroll
  for (int m = 0; m < 8; ++m)
#pragma unroll
    for (int n = 0; n < 4; ++n) {
      int col = n0 + wc * 64 + n * 16 + lr;
#pragma unroll
      for (int r = 0; r < 4; ++r)
        __builtin_nontemporal_store(acc[m][n][r] + bv[n],
                                    &out[(size_t)(rbase + m * 16 + r) * OUT_F + col]);
    }
}

// ---------------------------------------------------------------------------
// Fallback GEMM (proven round-1 kernel): 128x128 tile, m97 structure, 859 TF.
__global__ __launch_bounds__(256) void gemm_bias(const u16* __restrict__ Xb,
                                                 const u16* __restrict__ Wb,
                                                 const float* __restrict__ bias,
                                                 float* __restrict__ out) {
  __shared__ __align__(16) u16 ldsA[128 * 64];
  __shared__ __align__(16) u16 ldsB[128 * 64];

  const int tid  = threadIdx.x;
  const int wid  = tid >> 6;
  const int lane = tid & 63;
  const int nt = blockIdx.x & 31;
  const int mt = blockIdx.x >> 5;
  const int m0 = mt * 128, n0 = nt * 128;
  const int wr = wid >> 1, wc = wid & 1;
  const int lr = lane & 15;
  const int kg = lane >> 4;

  const int srow   = wid * 8 + (lane >> 3);
  const int schunk = (lane & 7) ^ (srow & 7);
  const u16* aSrc = Xb + (size_t)(m0 + srow) * IN_F + schunk * 8;
  const u16* bSrc = Wb + (size_t)(n0 + srow) * IN_F + schunk * 8;

  f32x4 acc[4][4] = {};

  for (int kt = 0; kt < IN_F; kt += 64) {
    __syncthreads();
#pragma unroll
    for (int j = 0; j < 4; ++j) {
      gload_lds16(aSrc + (size_t)(j * 32) * IN_F + kt, &ldsA[j * 2048 + wid * 512]);
      gload_lds16(bSrc + (size_t)(j * 32) * IN_F + kt, &ldsB[j * 2048 + wid * 512]);
    }
    __syncthreads();

#pragma unroll
    for (int s = 0; s < 2; ++s) {
      bf16x8 af[4], bfr[4];
#pragma unroll
      for (int m = 0; m < 4; ++m) {
        int r = wr * 64 + m * 16 + lr;
        int c = (s * 4 + kg) ^ (r & 7);
        af[m] = *(const bf16x8*)&ldsA[r * 64 + c * 8];
      }
#pragma unroll
      for (int n = 0; n < 4; ++n) {
        int r = wc * 64 + n * 16 + lr;
        int c = (s * 4 + kg) ^ (r & 7);
        bfr[n] = *(const bf16x8*)&ldsB[r * 64 + c * 8];
      }
#pragma unroll
      for (int m = 0; m < 4; ++m)
#pragma unroll
        for (int n = 0; n < 4; ++n)
          acc[m][n] = __builtin_amdgcn_mfma_f32_16x16x32_bf16(af[m], bfr[n], acc[m][n], 0, 0, 0);
    }
  }

  float bv[4];
#pragma unroll
  for (int n = 0; n < 4; ++n) bv[n] = bias[n0 + wc * 64 + n * 16 + lr];
  const int rbase = m0 + wr * 64 + kg * 4;
#pragma unroll
  for (int m = 0; m < 4; ++m)
#pragma unroll
    for (int n = 0; n < 4; ++n) {
      int col = n0 + wc * 64 + n * 16 + lr;
#pragma unroll
      for (int r = 0; r < 4; ++r)
        out[(size_t)(rbase + m * 16 + r) * OUT_F + col] = acc[m][n][r] + bv[n];
    }
}

// ---------------------------------------------------------------------------
// fp32 fallback (tiny workspace): exact, slow but correct.
__global__ void lora_t(const float* __restrict__ x, const float* __restrict__ B,
                       float* __restrict__ t) {
  int m = blockIdx.x;
  int tid = threadIdx.x, lane = tid & 63;
  float p[8] = {0, 0, 0, 0, 0, 0, 0, 0};
  for (int k = tid; k < IN_F; k += 256) {
    float xv = x[(size_t)m * IN_F + k];
#pragma unroll
    for (int r = 0; r < 8; ++r) p[r] += xv * B[r * IN_F + k];
  }
#pragma unroll
  for (int r = 0; r < 8; ++r) {
    float v = p[r];
    for (int off = 32; off; off >>= 1) v += __shfl_down(v, off);
    if (lane == 0) atomicAdd(&t[m * 8 + r], v);
  }
}

__global__ void fb_gemm(const float* __restrict__ x, const float* __restrict__ W,
                        const float* __restrict__ A, const float* __restrict__ bias,
                        const float* __restrict__ t, float* __restrict__ out) {
  __shared__ float sx[64][17];
  __shared__ float sw[64][17];
  int tx = threadIdx.x, ty = threadIdx.y;
  int tid = ty * 16 + tx;
  int m0 = blockIdx.y * 64, n0 = blockIdx.x * 64;
  float acc[4][4] = {};
  for (int kt = 0; kt < IN_F; kt += 16) {
    __syncthreads();
#pragma unroll
    for (int q = 0; q < 4; ++q) {
      int idx = q * 256 + tid;
      int r = idx >> 4, c = idx & 15;
      sx[r][c] = x[(size_t)(m0 + r) * IN_F + kt + c];
      sw[r][c] = W[(size_t)(n0 + r) * IN_F + kt + c];
    }
    __syncthreads();
#pragma unroll
    for (int k = 0; k < 16; ++k) {
      float xv[4], wv[4];
#pragma unroll
      for (int i = 0; i < 4; ++i) xv[i] = sx[ty * 4 + i][k];
#pragma unroll
      for (int j = 0; j < 4; ++j) wv[j] = sw[tx * 4 + j][k];
#pragma unroll
      for (int i = 0; i < 4; ++i)
#pragma unroll
        for (int j = 0; j < 4; ++j) acc[i][j] += xv[i] * wv[j];
    }
  }
#pragma unroll
  for (int i = 0; i < 4; ++i) {
    int m = m0 + ty * 4 + i;
    float tv[8];
#pragma unroll
    for (int r = 0; r < 8; ++r) tv[r] = t[m * 8 + r];
#pragma unroll
    for (int j = 0; j < 4; ++j) {
      int o = n0 + tx * 4 + j;
      float lora = 0.f;
#pragma unroll
      for (int r = 0; r < 8; ++r) lora += tv[r] * A[o * 8 + r];
      out[(size_t)m * OUT_F + o] = acc[i][j] + bias[o] + LORA_SCALE * lora;
    }
  }
}

// ---------------------------------------------------------------------------
extern "C" void kernel_launch(void* const* d_in, const int* in_sizes, int n_in,
                              void* d_out, int out_size, void* d_ws, size_t ws_size,
                              hipStream_t stream) {
  const float* x    = (const float*)d_in[0];
  const float* W    = (const float*)d_in[1];
  const float* A    = (const float*)d_in[2];
  const float* B    = (const float*)d_in[3];
  const float* bias = (const float*)d_in[4];
  float* out = (float*)d_out;

  const size_t xb_elems = (size_t)M_TOT * IN_F;
  const size_t wb_elems = (size_t)OUT_F * IN_F;
  const size_t need = (xb_elems + wb_elems) * sizeof(u16);

  if (ws_size >= need) {
    u16* Xb = (u16*)d_ws;
    u16* Wb = Xb + xb_elems;
    prep<<<32768, 256, 0, stream>>>(x, W, A, B, Xb, Wb);

    hipError_t e = hipFuncSetAttribute((const void*)gemm8,
                                       hipFuncAttributeMaxDynamicSharedMemorySize,
                                       131072);
    bool used8 = false;
    if (e == hipSuccess) {
      gemm8<<<512, 512, 131072, stream>>>(Xb, Wb, bias, out);
      used8 = (hipGetLastError() == hipSuccess);
    }
    if (!used8) {
      gemm_bias<<<(M_TOT / 128) * (OUT_F / 128), 256, 0, stream>>>(Xb, Wb, bias, out);
    }
  } else {
    float* t = (float*)d_ws;
    (void)hipMemsetAsync(t, 0, (size_t)M_TOT * 8 * sizeof(float), stream);
    lora_t<<<M_TOT, 256, 0, stream>>>(x, B, t);
    fb_gemm<<<dim3(OUT_F / 64, M_TOT / 64), dim3(16, 16), 0, stream>>>(x, W, A, bias, t, out);
  }
}